// Round 1
// baseline (814.774 us; speedup 1.0000x reference)
//
#include <hip/hip_runtime.h>
#include <math.h>

#define NPIX 4096   // H*W
#define NB   4      // batch
#define CDIM 256
#define DQK  32

// ============================================================================
// Projection kernel: out = W (MxC) @ X (CxN) + bias, per batch.
//   M=32,  OUT_CN=false : out[b][n][32]   (q, k layouts for attention staging)
//   M=256, OUT_CN=true  : out[b][c][n]    (v layout -> conflict-free VT staging)
// Block: 256 threads, tile = M x 64 pixels. Thread: (cg = t>>3, np = t&7),
// owns CPT=M/32 channels x 8 pixels. K-loop over C in slabs of 16 staged in LDS.
// ============================================================================
template<int M, bool OUT_CN>
__global__ __launch_bounds__(256, 2)
void proj_kernel(const float* __restrict__ X, const float* __restrict__ W,
                 const float* __restrict__ bias, float* __restrict__ out) {
  constexpr int WS = M + 4;           // padded WT row (breaks stage-write conflicts)
  __shared__ float sX[16 * 64];       // X slab [c'][n]
  __shared__ float sWT[16 * WS];      // W slab transposed [c'][c]
  const int t  = threadIdx.x;
  const int b  = blockIdx.y;
  const int n0 = blockIdx.x * 64;
  const int cg = t >> 3;              // 0..31
  const int np = t & 7;               // 0..7
  constexpr int CPT = M / 32;         // 8 (v) or 1 (q,k)

  float acc[CPT][8];
  #pragma unroll
  for (int a = 0; a < CPT; a++)
    #pragma unroll
    for (int j = 0; j < 8; j++) acc[a][j] = 0.f;

  const float* Xb = X + (size_t)b * CDIM * NPIX;

  for (int cs = 0; cs < CDIM; cs += 16) {
    __syncthreads();
    // stage X slab [16][64] (coalesced global, linear LDS)
    #pragma unroll
    for (int i = 0; i < 4; i++) {
      int f = i * 256 + t;
      int r = f >> 6, col = f & 63;
      sX[r * 64 + col] = Xb[(size_t)(cs + r) * NPIX + n0 + col];
    }
    // stage W slab transposed [16][M] (pad WS -> 2-way max on writes)
    #pragma unroll
    for (int i = 0; i < M / 16; i++) {
      int f = i * 256 + t;
      int c = f >> 4, cr = f & 15;
      sWT[cr * WS + c] = W[c * CDIM + cs + cr];
    }
    __syncthreads();
    #pragma unroll
    for (int cp = 0; cp < 16; cp++) {
      float xr[8];
      float4 x0 = *(const float4*)&sX[cp * 64 + np * 8];
      float4 x1 = *(const float4*)&sX[cp * 64 + np * 8 + 4];
      xr[0] = x0.x; xr[1] = x0.y; xr[2] = x0.z; xr[3] = x0.w;
      xr[4] = x1.x; xr[5] = x1.y; xr[6] = x1.z; xr[7] = x1.w;
      if constexpr (M == 256) {
        float wr[8];
        float4 w0 = *(const float4*)&sWT[cp * WS + cg * 8];
        float4 w1 = *(const float4*)&sWT[cp * WS + cg * 8 + 4];
        wr[0] = w0.x; wr[1] = w0.y; wr[2] = w0.z; wr[3] = w0.w;
        wr[4] = w1.x; wr[5] = w1.y; wr[6] = w1.z; wr[7] = w1.w;
        #pragma unroll
        for (int a = 0; a < CPT; a++)
          #pragma unroll
          for (int j = 0; j < 8; j++)
            acc[a][j] = fmaf(wr[a], xr[j], acc[a][j]);
      } else {
        float w = sWT[cp * WS + cg];
        #pragma unroll
        for (int j = 0; j < 8; j++)
          acc[0][j] = fmaf(w, xr[j], acc[0][j]);
      }
    }
  }

  if constexpr (OUT_CN) {
    // v: out[b][c][n], contiguous-n float4 stores
    #pragma unroll
    for (int a = 0; a < CPT; a++) {
      int c = cg * 8 + a;
      float bv = bias[c];
      float o[8];
      #pragma unroll
      for (int j = 0; j < 8; j++) o[j] = acc[a][j] + bv;
      size_t base = ((size_t)b * CDIM + c) * NPIX + n0 + np * 8;
      *(float4*)&out[base]     = make_float4(o[0], o[1], o[2], o[3]);
      *(float4*)&out[base + 4] = make_float4(o[4], o[5], o[6], o[7]);
    }
  } else {
    // q,k: out[b][n][M], one channel per thread
    float bv = bias[cg];
    #pragma unroll
    for (int j = 0; j < 8; j++) {
      int n = n0 + np * 8 + j;
      out[((size_t)b * NPIX + n) * M + cg] = acc[0][j] + bv;
    }
  }
}

// ============================================================================
// Flash attention (fp32, online softmax). Grid 512 blocks x 256 threads.
// Block = (batch b, 32-query tile). Iterates 128 key-tiles of 32.
// LDS: Q[32][33], KT[32][36], VT[256][36] (V transposed: row c, cols = key
// slot, padded to 36 -> float4 reads 4-way max), S[32][33], PT[32][36],
// partial sums, m/l/alpha.  PV thread tile: 8q x 8c x 16k (kh split),
// c interleaved (c = cg + 32*i).  Epilogue reduces the two k-halves via LDS.
// XCD swizzle: bid&7 -> XCD (round-robin dispatch), 2 XCDs per batch so each
// XCD's 4MB L2 holds its half-batch K/V working set.
// ============================================================================
__global__ __launch_bounds__(256, 2)
void attn_kernel(const float* __restrict__ Qw, const float* __restrict__ Kw,
                 const float* __restrict__ Vw, float* __restrict__ out) {
  __shared__ float smem[13984];
  float* sQ    = smem;            // [32][33]
  float* sKT   = smem + 1056;     // [32][36]  KT[d][k]
  float* sVT   = smem + 2208;     // [256][36] VT[c][k] (9216 floats)
  float* sS    = smem + 11424;    // [32][33]
  float* sPT   = smem + 12480;    // [32][36]  P[q][k]
  float* sPart = smem + 13632;    // [8][32]
  float* sM    = smem + 13888;    // [32]
  float* sL    = smem + 13920;    // [32]
  float* sA    = smem + 13952;    // [32]

  const int t    = threadIdx.x;
  const int bid  = blockIdx.x;
  const int xcd  = bid & 7;
  const int slot = bid >> 3;
  const int b    = xcd >> 1;                       // 2 XCDs per batch
  const int n0   = (((xcd & 1) << 6) + slot) * 32; // query-tile origin

  const float* Qb = Qw + (size_t)b * NPIX * DQK;
  const float* Kb = Kw + (size_t)b * NPIX * DQK;
  const float* Vb = Vw + (size_t)b * CDIM * NPIX;

  // stage Q tile [32][32] -> [32][33]
  #pragma unroll
  for (int i = 0; i < 4; i++) {
    int f = i * 256 + t;
    int q = f >> 5, d = f & 31;
    sQ[q * 33 + d] = Qb[(size_t)(n0 + q) * DQK + d];
  }
  if (t < 32) { sM[t] = -INFINITY; sL[t] = 0.f; }

  float acc[8][8];
  #pragma unroll
  for (int j = 0; j < 8; j++)
    #pragma unroll
    for (int i = 0; i < 8; i++) acc[j][i] = 0.f;

  const int kh = t >> 7;          // k-half
  const int qg = (t >> 5) & 3;    // query group
  const int cg = t & 31;          // channel lane
  const int q0 = qg * 8;

  for (int kt = 0; kt < 128; kt++) {
    const int nk = kt * 32;
    __syncthreads();              // previous tile's LDS consumers done
    { // stage K tile transposed: KT[d][k]
      int kk = t >> 3, f4 = t & 7;
      float4 kv = *(const float4*)&Kb[(size_t)(nk + kk) * DQK + f4 * 4];
      sKT[(f4 * 4 + 0) * 36 + kk] = kv.x;
      sKT[(f4 * 4 + 1) * 36 + kk] = kv.y;
      sKT[(f4 * 4 + 2) * 36 + kk] = kv.z;
      sKT[(f4 * 4 + 3) * 36 + kk] = kv.w;
    }
    // stage V tile: VT[c][k] straight from v's [c][n] layout (coalesced, no transpose)
    #pragma unroll
    for (int i = 0; i < 8; i++) {
      int f = i * 256 + t;
      int c = f >> 3, nn4 = f & 7;
      float4 vv = *(const float4*)&Vb[(size_t)c * NPIX + nk + nn4 * 4];
      *(float4*)&sVT[c * 36 + nn4 * 4] = vv;
    }
    __syncthreads();
    { // S[q][k] = Q . K  (thread: q = t&31, 4 k's)
      int q = t & 31, k4 = t >> 5;
      float s0 = 0, s1 = 0, s2 = 0, s3 = 0;
      #pragma unroll
      for (int d = 0; d < 32; d++) {
        float qv = sQ[q * 33 + d];
        float4 kv = *(const float4*)&sKT[d * 36 + k4 * 4];
        s0 = fmaf(qv, kv.x, s0); s1 = fmaf(qv, kv.y, s1);
        s2 = fmaf(qv, kv.z, s2); s3 = fmaf(qv, kv.w, s3);
      }
      sS[q * 33 + k4 * 4 + 0] = s0;
      sS[q * 33 + k4 * 4 + 1] = s1;
      sS[q * 33 + k4 * 4 + 2] = s2;
      sS[q * 33 + k4 * 4 + 3] = s3;
    }
    __syncthreads();
    if (t < 32) { // online-softmax row stats
      float m = sS[t * 33];
      #pragma unroll
      for (int k = 1; k < 32; k++) m = fmaxf(m, sS[t * 33 + k]);
      float mold = sM[t], mnew = fmaxf(mold, m);
      sM[t] = mnew;
      sA[t] = __expf(mold - mnew);
    }
    __syncthreads();
    { // P = exp(S - m), partial row sums
      int q = t & 31, k4 = t >> 5;
      float mnew = sM[q];
      float p0 = __expf(sS[q * 33 + k4 * 4 + 0] - mnew);
      float p1 = __expf(sS[q * 33 + k4 * 4 + 1] - mnew);
      float p2 = __expf(sS[q * 33 + k4 * 4 + 2] - mnew);
      float p3 = __expf(sS[q * 33 + k4 * 4 + 3] - mnew);
      sPT[q * 36 + k4 * 4 + 0] = p0;
      sPT[q * 36 + k4 * 4 + 1] = p1;
      sPT[q * 36 + k4 * 4 + 2] = p2;
      sPT[q * 36 + k4 * 4 + 3] = p3;
      sPart[k4 * 32 + q] = (p0 + p1) + (p2 + p3);
    }
    __syncthreads();
    if (t < 32) { // finish l update (runs alongside PV below)
      float s = 0;
      #pragma unroll
      for (int j = 0; j < 8; j++) s += sPart[j * 32 + t];
      sL[t] = sL[t] * sA[t] + s;
    }
    { // PV: acc = acc*alpha + P . V   (8q x 8c x 16k per thread)
      float al[8];
      #pragma unroll
      for (int j = 0; j < 8; j++) al[j] = sA[q0 + j];
      #pragma unroll
      for (int j = 0; j < 8; j++)
        #pragma unroll
        for (int i = 0; i < 8; i++) acc[j][i] *= al[j];
      #pragma unroll
      for (int k4 = 0; k4 < 4; k4++) {
        const int kk4 = kh * 4 + k4;
        float4 p4[8];
        #pragma unroll
        for (int j = 0; j < 8; j++)
          p4[j] = *(const float4*)&sPT[(q0 + j) * 36 + kk4 * 4];
        #pragma unroll
        for (int i = 0; i < 8; i++) {
          float4 v4 = *(const float4*)&sVT[(cg + 32 * i) * 36 + kk4 * 4];
          #pragma unroll
          for (int j = 0; j < 8; j++) {
            acc[j][i] = fmaf(p4[j].x, v4.x, acc[j][i]);
            acc[j][i] = fmaf(p4[j].y, v4.y, acc[j][i]);
            acc[j][i] = fmaf(p4[j].z, v4.z, acc[j][i]);
            acc[j][i] = fmaf(p4[j].w, v4.w, acc[j][i]);
          }
        }
      }
    }
  }

  // epilogue: reduce the two k-halves, divide by l, write out[b][c][n]
  __syncthreads();
  float* red = sVT; // reuse (needs 8192 floats, VT has 9216)
  if (kh == 1) {
    #pragma unroll
    for (int j = 0; j < 8; j++)
      #pragma unroll
      for (int i = 0; i < 8; i++)
        red[(t - 128) * 64 + j * 8 + i] = acc[j][i];
  }
  __syncthreads();
  if (kh == 0) {
    float linv[8];
    #pragma unroll
    for (int j = 0; j < 8; j++) linv[j] = 1.f / sL[q0 + j];
    #pragma unroll
    for (int i = 0; i < 8; i++) {
      int c = cg + 32 * i;
      float o[8];
      #pragma unroll
      for (int j = 0; j < 8; j++)
        o[j] = (acc[j][i] + red[t * 64 + j * 8 + i]) * linv[j];
      size_t base = ((size_t)b * CDIM + c) * NPIX + n0 + q0;
      *(float4*)&out[base]     = make_float4(o[0], o[1], o[2], o[3]);
      *(float4*)&out[base + 4] = make_float4(o[4], o[5], o[6], o[7]);
    }
  }
}

// ============================================================================
extern "C" void kernel_launch(void* const* d_in, const int* in_sizes, int n_in,
                              void* d_out, int out_size, void* d_ws, size_t ws_size,
                              hipStream_t stream) {
  const float* f1 = (const float*)d_in[0];
  const float* f2 = (const float*)d_in[1];
  const float* Wq = (const float*)d_in[2];
  const float* bq = (const float*)d_in[3];
  const float* Wk = (const float*)d_in[4];
  const float* bk = (const float*)d_in[5];
  const float* Wv = (const float*)d_in[6];
  const float* bv = (const float*)d_in[7];
  float* outp = (float*)d_out;

  float* ws = (float*)d_ws;
  float* Qw = ws;                       // [4][4096][32]  = 524288 floats
  float* Kw = ws + 524288;              // [4][4096][32]
  float* Vw = ws + 1048576;             // [4][256][4096] = 4194304 floats
  // total ws use: 5242880 floats = 20 MiB

  dim3 pgrid(NPIX / 64, NB);
  proj_kernel<32, false><<<pgrid, 256, 0, stream>>>(f1, Wq, bq, Qw);
  proj_kernel<32, false><<<pgrid, 256, 0, stream>>>(f2, Wk, bk, Kw);
  proj_kernel<256, true><<<pgrid, 256, 0, stream>>>(f2, Wv, bv, Vw);

  attn_kernel<<<dim3(512), 256, 0, stream>>>(Qw, Kw, Vw, outp);
}

// Round 2
// 356.536 us; speedup vs baseline: 2.2852x; 2.2852x over previous
//
#include <hip/hip_runtime.h>
#include <math.h>

#define NPIX 4096   // H*W
#define NB   4      // batch
#define CDIM 256
#define DQK  32

typedef short short8v __attribute__((ext_vector_type(8)));   // 8 bf16 (MFMA A/B frag)
typedef float f32x16  __attribute__((ext_vector_type(16)));  // 32x32 MFMA C/D frag
typedef unsigned short u16x8 __attribute__((ext_vector_type(8)));

// RNE float -> bf16 (finite inputs only)
__device__ __forceinline__ unsigned short f2bf(float x) {
  unsigned int u = __float_as_uint(x);
  u += 0x7fffu + ((u >> 16) & 1u);
  return (unsigned short)(u >> 16);
}
__device__ __forceinline__ float bf2f(unsigned short h) {
  return __uint_as_float(((unsigned int)h) << 16);
}

// ============================================================================
// Projection: out = W (MxC) @ X (CxN) + bias, emitted as bf16 hi/lo planes.
//   M=32,  OUT_CN=false : planes [b][n][32]   (q, k: MFMA B/A frag friendly)
//   M=256, OUT_CN=true  : planes [b][c][n]    (v: row-major in m for staging)
// ============================================================================
template<int M, bool OUT_CN>
__global__ __launch_bounds__(256, 2)
void proj_kernel(const float* __restrict__ X, const float* __restrict__ W,
                 const float* __restrict__ bias,
                 unsigned short* __restrict__ OH, unsigned short* __restrict__ OL) {
  constexpr int WS = M + 4;
  __shared__ float sX[16 * 64];
  __shared__ float sWT[16 * WS];
  const int t  = threadIdx.x;
  const int b  = blockIdx.y;
  const int n0 = blockIdx.x * 64;
  const int cg = t >> 3;
  const int np = t & 7;
  constexpr int CPT = M / 32;

  float acc[CPT][8];
  #pragma unroll
  for (int a = 0; a < CPT; a++)
    #pragma unroll
    for (int j = 0; j < 8; j++) acc[a][j] = 0.f;

  const float* Xb = X + (size_t)b * CDIM * NPIX;

  for (int cs = 0; cs < CDIM; cs += 16) {
    __syncthreads();
    #pragma unroll
    for (int i = 0; i < 4; i++) {
      int f = i * 256 + t;
      int r = f >> 6, col = f & 63;
      sX[r * 64 + col] = Xb[(size_t)(cs + r) * NPIX + n0 + col];
    }
    #pragma unroll
    for (int i = 0; i < M / 16; i++) {
      int f = i * 256 + t;
      int c = f >> 4, cr = f & 15;
      sWT[cr * WS + c] = W[c * CDIM + cs + cr];
    }
    __syncthreads();
    #pragma unroll
    for (int cp = 0; cp < 16; cp++) {
      float xr[8];
      float4 x0 = *(const float4*)&sX[cp * 64 + np * 8];
      float4 x1 = *(const float4*)&sX[cp * 64 + np * 8 + 4];
      xr[0] = x0.x; xr[1] = x0.y; xr[2] = x0.z; xr[3] = x0.w;
      xr[4] = x1.x; xr[5] = x1.y; xr[6] = x1.z; xr[7] = x1.w;
      if constexpr (M == 256) {
        float wr[8];
        float4 w0 = *(const float4*)&sWT[cp * WS + cg * 8];
        float4 w1 = *(const float4*)&sWT[cp * WS + cg * 8 + 4];
        wr[0] = w0.x; wr[1] = w0.y; wr[2] = w0.z; wr[3] = w0.w;
        wr[4] = w1.x; wr[5] = w1.y; wr[6] = w1.z; wr[7] = w1.w;
        #pragma unroll
        for (int a = 0; a < CPT; a++)
          #pragma unroll
          for (int j = 0; j < 8; j++)
            acc[a][j] = fmaf(wr[a], xr[j], acc[a][j]);
      } else {
        float w = sWT[cp * WS + cg];
        #pragma unroll
        for (int j = 0; j < 8; j++)
          acc[0][j] = fmaf(w, xr[j], acc[0][j]);
      }
    }
  }

  if constexpr (OUT_CN) {
    #pragma unroll
    for (int a = 0; a < CPT; a++) {
      int c = cg * 8 + a;
      float bv = bias[c];
      u16x8 hv, lv;
      #pragma unroll
      for (int j = 0; j < 8; j++) {
        float o = acc[a][j] + bv;
        unsigned short h = f2bf(o);
        hv[j] = h;
        lv[j] = f2bf(o - bf2f(h));
      }
      size_t base = ((size_t)b * CDIM + c) * NPIX + n0 + np * 8;
      *(u16x8*)&OH[base] = hv;
      *(u16x8*)&OL[base] = lv;
    }
  } else {
    float bv = bias[cg];
    #pragma unroll
    for (int j = 0; j < 8; j++) {
      int n = n0 + np * 8 + j;
      float o = acc[0][j] + bv;
      unsigned short h = f2bf(o);
      size_t idx = ((size_t)b * NPIX + n) * DQK + cg;
      OH[idx] = h;
      OL[idx] = f2bf(o - bf2f(h));
    }
  }
}

// ============================================================================
// MFMA flash attention, bf16 split precision (hi+lo, 3-product MFMA).
// Grid 512 = 4 batches x 128 q-tiles(32). Block 256 thr = 4 waves, 2 blk/CU.
// Wave w: PV c-quarter [64w, 64w+64); waves 0,1 additionally own QK^T k-half.
// Swapped QK^T: S^T[k][n] = mfma(K, Q^T) so the k-reduction is lane-local.
// K frags: straight from global (L2). V: LDS [c][m] hi/lo planes, XOR-swizzled
// 16B chunks. P: LDS round-trip [n][m] hi/lo, same swizzle.
// ============================================================================
__global__ __launch_bounds__(256, 2)
void attn_kernel(const unsigned short* __restrict__ QH, const unsigned short* __restrict__ QL,
                 const unsigned short* __restrict__ KH, const unsigned short* __restrict__ KL,
                 const unsigned short* __restrict__ VH, const unsigned short* __restrict__ VL,
                 float* __restrict__ out) {
  __shared__ __attribute__((aligned(16))) unsigned short sVH[CDIM * 64];
  __shared__ __attribute__((aligned(16))) unsigned short sVL[CDIM * 64];
  __shared__ __attribute__((aligned(16))) unsigned short sPH[32 * 64];
  __shared__ __attribute__((aligned(16))) unsigned short sPL[32 * 64];
  __shared__ __attribute__((aligned(16))) float sPM[2][32];
  __shared__ __attribute__((aligned(16))) float sL[2][32];

  const int t  = threadIdx.x;
  const int w  = t >> 6;        // wave 0..3
  const int l  = t & 63;        // lane
  const int ln = l & 31;        // n-col (S^T) / n-row (PV A) / c-lane (PV B)
  const int g  = l >> 5;        // frag k-group (l/32)
  const int hh = g;             // D-frag half selector

  const int bid = blockIdx.x;
  const int xcd = bid & 7;                       // round-robin dispatch -> XCD
  const int b   = xcd >> 1;                      // batch pinned to XCD pair
  const int qt  = ((bid >> 3) << 1) | (xcd & 1); // q-tile 0..127
  const int n0  = qt * 32;

  // ---- Q fragments hoisted to registers (waves 0,1: B operand of S^T) ----
  short8v qh[2], ql[2];
  if (w < 2) {
    const unsigned short* qr  = QH + ((size_t)b * NPIX + n0 + ln) * DQK + 8 * g;
    const unsigned short* qrL = QL + ((size_t)b * NPIX + n0 + ln) * DQK + 8 * g;
    qh[0] = *(const short8v*)(qr);       qh[1] = *(const short8v*)(qr + 16);
    ql[0] = *(const short8v*)(qrL);      ql[1] = *(const short8v*)(qrL + 16);
  }

  f32x16 acc0, acc1;
  float m_acc[16], alpha[16];
  #pragma unroll
  for (int r = 0; r < 16; ++r) { acc0[r] = 0.f; acc1[r] = 0.f; m_acc[r] = -INFINITY; }
  float m_s = -INFINITY, l_part = 0.f;

  const int r0 = t >> 3;   // staging row group 0..31
  const int ch = t & 7;    // staging chunk
  const int vsw0 = ch ^ (r0 & 7);

  for (int kt = 0; kt < 64; ++kt) {
    const int m0 = kt * 64;

    // K fragments from global (A operand of S^T): row k = m0 + 32w + ln
    short8v kh[2], kl[2];
    if (w < 2) {
      const size_t kbase = ((size_t)b * NPIX + m0 + 32 * w + ln) * DQK + 8 * g;
      kh[0] = *(const short8v*)&KH[kbase];      kh[1] = *(const short8v*)&KH[kbase + 16];
      kl[0] = *(const short8v*)&KL[kbase];      kl[1] = *(const short8v*)&KL[kbase + 16];
    }

    __syncthreads();  // [A] prev tile's LDS consumers done

    // ---- stage V tile: [c][m] hi/lo planes, swizzled 16B chunks ----
    {
      const size_t gbase = (size_t)b * CDIM * NPIX + m0 + ch * 8;
      #pragma unroll 4
      for (int i = 0; i < 8; ++i) {
        int r = i * 32 + r0;
        u16x8 v = *(const u16x8*)&VH[gbase + (size_t)r * NPIX];
        *(u16x8*)&sVH[r * 64 + (vsw0 << 3)] = v;
      }
      #pragma unroll 4
      for (int i = 0; i < 8; ++i) {
        int r = i * 32 + r0;
        u16x8 v = *(const u16x8*)&VL[gbase + (size_t)r * NPIX];
        *(u16x8*)&sVL[r * 64 + (vsw0 << 3)] = v;
      }
    }

    // ---- QK^T (waves 0,1): S^T = K.Q^T with hi/lo split ----
    f32x16 sT;
    if (w < 2) {
      #pragma unroll
      for (int r = 0; r < 16; ++r) sT[r] = 0.f;
      #pragma unroll
      for (int s = 0; s < 2; ++s) {
        sT = __builtin_amdgcn_mfma_f32_32x32x16_bf16(kh[s], qh[s], sT, 0, 0, 0);
        sT = __builtin_amdgcn_mfma_f32_32x32x16_bf16(kh[s], ql[s], sT, 0, 0, 0);
        sT = __builtin_amdgcn_mfma_f32_32x32x16_bf16(kl[s], qh[s], sT, 0, 0, 0);
      }
      float pm = sT[0];
      #pragma unroll
      for (int r = 1; r < 16; ++r) pm = fmaxf(pm, sT[r]);
      pm = fmaxf(pm, __shfl_xor(pm, 32));
      if (l < 32) sPM[w][l] = pm;   // per-n max over this 32-key half
    }

    __syncthreads();  // [B] V staged + sPM ready

    // ---- m update + acc rescale (all waves; acc rows n = (r&3)+8(r>>2)+4hh) ----
    #pragma unroll
    for (int rq = 0; rq < 4; ++rq) {
      const float4 p0 = *(const float4*)&sPM[0][8 * rq + 4 * hh];
      const float4 p1 = *(const float4*)&sPM[1][8 * rq + 4 * hh];
      float mn;
      mn = fmaxf(m_acc[4*rq+0], fmaxf(p0.x, p1.x));
      alpha[4*rq+0] = __expf(m_acc[4*rq+0] - mn); m_acc[4*rq+0] = mn;
      mn = fmaxf(m_acc[4*rq+1], fmaxf(p0.y, p1.y));
      alpha[4*rq+1] = __expf(m_acc[4*rq+1] - mn); m_acc[4*rq+1] = mn;
      mn = fmaxf(m_acc[4*rq+2], fmaxf(p0.z, p1.z));
      alpha[4*rq+2] = __expf(m_acc[4*rq+2] - mn); m_acc[4*rq+2] = mn;
      mn = fmaxf(m_acc[4*rq+3], fmaxf(p0.w, p1.w));
      alpha[4*rq+3] = __expf(m_acc[4*rq+3] - mn); m_acc[4*rq+3] = mn;
    }
    #pragma unroll
    for (int r = 0; r < 16; ++r) { acc0[r] *= alpha[r]; acc1[r] *= alpha[r]; }

    // ---- P = exp(S^T - m), split to bf16 hi/lo, packed b32 LDS writes ----
    if (w < 2) {
      const float mo = m_s;
      const float mN = fmaxf(mo, fmaxf(sPM[0][ln], sPM[1][ln]));
      m_s = mN;
      float ps = 0.f;
      unsigned int hw[8], lw[8];
      #pragma unroll
      for (int r = 0; r < 16; r += 2) {
        float p0 = __expf(sT[r] - mN);
        float p1 = __expf(sT[r + 1] - mN);
        ps += p0 + p1;
        unsigned short h0 = f2bf(p0), h1 = f2bf(p1);
        unsigned short l0 = f2bf(p0 - bf2f(h0)), l1 = f2bf(p1 - bf2f(h1));
        hw[r >> 1] = (unsigned int)h0 | ((unsigned int)h1 << 16);
        lw[r >> 1] = (unsigned int)l0 | ((unsigned int)l1 << 16);
      }
      ps += __shfl_xor(ps, 32);
      l_part = l_part * __expf(mo - mN) + ps;
      #pragma unroll
      for (int r = 0; r < 16; r += 2) {
        const int k   = 32 * w + (r & 3) + 8 * (r >> 2) + 4 * hh;
        const int off = ln * 64 + (((k >> 3) ^ (ln & 7)) << 3) + (k & 7);
        *(unsigned int*)&sPH[off] = hw[r >> 1];
        *(unsigned int*)&sPL[off] = lw[r >> 1];
      }
    }

    __syncthreads();  // [C] P ready

    // ---- PV: acc += P.V^T (hi/lo split), A-frags shared across c-frags ----
    short8v pah[4], pal[4];
    {
      const int pbase = ln * 64;
      #pragma unroll
      for (int s = 0; s < 4; ++s) {
        const int off = pbase + ((((2 * s + g)) ^ (ln & 7)) << 3);
        pah[s] = *(const short8v*)&sPH[off];
        pal[s] = *(const short8v*)&sPL[off];
      }
    }
    {
      const int c0  = 64 * w + ln;
      const int vsw = c0 & 7;   // (c0+32)&7 == c0&7
      #pragma unroll
      for (int s = 0; s < 4; ++s) {
        const int chk = (((2 * s + g)) ^ vsw) << 3;
        short8v vh0 = *(const short8v*)&sVH[c0 * 64 + chk];
        short8v vl0 = *(const short8v*)&sVL[c0 * 64 + chk];
        acc0 = __builtin_amdgcn_mfma_f32_32x32x16_bf16(pah[s], vh0, acc0, 0, 0, 0);
        acc0 = __builtin_amdgcn_mfma_f32_32x32x16_bf16(pah[s], vl0, acc0, 0, 0, 0);
        acc0 = __builtin_amdgcn_mfma_f32_32x32x16_bf16(pal[s], vh0, acc0, 0, 0, 0);
        short8v vh1 = *(const short8v*)&sVH[(c0 + 32) * 64 + chk];
        short8v vl1 = *(const short8v*)&sVL[(c0 + 32) * 64 + chk];
        acc1 = __builtin_amdgcn_mfma_f32_32x32x16_bf16(pah[s], vh1, acc1, 0, 0, 0);
        acc1 = __builtin_amdgcn_mfma_f32_32x32x16_bf16(pah[s], vl1, acc1, 0, 0, 0);
        acc1 = __builtin_amdgcn_mfma_f32_32x32x16_bf16(pal[s], vh1, acc1, 0, 0, 0);
      }
    }
  }

  // ---- epilogue: merge k-half denominators, divide, store ----
  if (w < 2 && l < 32) sL[w][l] = l_part;
  __syncthreads();

  float4 linv[4];
  #pragma unroll
  for (int rq = 0; rq < 4; ++rq) {
    const float4 l0 = *(const float4*)&sL[0][8 * rq + 4 * hh];
    const float4 l1 = *(const float4*)&sL[1][8 * rq + 4 * hh];
    linv[rq].x = 1.f / (l0.x + l1.x);
    linv[rq].y = 1.f / (l0.y + l1.y);
    linv[rq].z = 1.f / (l0.z + l1.z);
    linv[rq].w = 1.f / (l0.w + l1.w);
  }

  const int c0 = 64 * w + ln;
  float* orow0 = out + ((size_t)b * CDIM + c0) * NPIX + n0;
  float* orow1 = out + ((size_t)b * CDIM + c0 + 32) * NPIX + n0;
  #pragma unroll
  for (int rq = 0; rq < 4; ++rq) {
    float4 o0, o1;
    o0.x = acc0[4*rq+0] * linv[rq].x;  o1.x = acc1[4*rq+0] * linv[rq].x;
    o0.y = acc0[4*rq+1] * linv[rq].y;  o1.y = acc1[4*rq+1] * linv[rq].y;
    o0.z = acc0[4*rq+2] * linv[rq].z;  o1.z = acc1[4*rq+2] * linv[rq].z;
    o0.w = acc0[4*rq+3] * linv[rq].w;  o1.w = acc1[4*rq+3] * linv[rq].w;
    *(float4*)&orow0[8 * rq + 4 * hh] = o0;
    *(float4*)&orow1[8 * rq + 4 * hh] = o1;
  }
}

// ============================================================================
extern "C" void kernel_launch(void* const* d_in, const int* in_sizes, int n_in,
                              void* d_out, int out_size, void* d_ws, size_t ws_size,
                              hipStream_t stream) {
  const float* f1 = (const float*)d_in[0];
  const float* f2 = (const float*)d_in[1];
  const float* Wq = (const float*)d_in[2];
  const float* bq = (const float*)d_in[3];
  const float* Wk = (const float*)d_in[4];
  const float* bk = (const float*)d_in[5];
  const float* Wv = (const float*)d_in[6];
  const float* bv = (const float*)d_in[7];

  unsigned short* ws = (unsigned short*)d_ws;
  unsigned short* QH = ws;                  // [4][4096][32]  1 MiB each plane
  unsigned short* QL = ws + 524288;
  unsigned short* KH = ws + 1048576;
  unsigned short* KL = ws + 1572864;
  unsigned short* VH = ws + 2097152;        // [4][256][4096] 8 MiB each plane
  unsigned short* VL = ws + 6291456;        // total 20 MiB

  dim3 pgrid(NPIX / 64, NB);
  proj_kernel<32,  false><<<pgrid, 256, 0, stream>>>(f1, Wq, bq, QH, QL);
  proj_kernel<32,  false><<<pgrid, 256, 0, stream>>>(f2, Wk, bk, KH, KL);
  proj_kernel<256, true ><<<pgrid, 256, 0, stream>>>(f2, Wv, bv, VH, VL);

  attn_kernel<<<dim3(512), 256, 0, stream>>>(QH, QL, KH, KL, VH, VL, (float*)d_out);
}

// Round 4
// 309.462 us; speedup vs baseline: 2.6329x; 1.1521x over previous
//
#include <hip/hip_runtime.h>
#include <math.h>

#define NPIX 4096   // H*W
#define NB   4      // batch
#define CDIM 256
#define DQK  32

typedef short short8v __attribute__((ext_vector_type(8)));   // 8 bf16 (MFMA A/B frag)
typedef float f32x16  __attribute__((ext_vector_type(16)));  // 32x32 MFMA C/D frag
typedef unsigned short u16x8 __attribute__((ext_vector_type(8)));

// RNE float -> bf16 (finite inputs only)
__device__ __forceinline__ unsigned short f2bf(float x) {
  unsigned int u = __float_as_uint(x);
  u += 0x7fffu + ((u >> 16) & 1u);
  return (unsigned short)(u >> 16);
}
__device__ __forceinline__ float bf2f(unsigned short h) {
  return __uint_as_float(((unsigned int)h) << 16);
}

#define MFMA32(A, B, C) __builtin_amdgcn_mfma_f32_32x32x16_bf16((A), (B), (C), 0, 0, 0)

// ============================================================================
// q/k projection (M=32): out planes [b][n][32] bf16 hi/lo.
// fp32 FMA compute; epilogue transposes through LDS so the [n][32] stores are
// coalesced u16x8 (round-2's scattered 2B scalar stores were ~50us each).
// ============================================================================
__global__ __launch_bounds__(256, 2)
void qkproj_kernel(const float* __restrict__ X, const float* __restrict__ W,
                   const float* __restrict__ bias,
                   unsigned short* __restrict__ OH, unsigned short* __restrict__ OL) {
  __shared__ float smem[2080];     // staging: sX[16*64]+sWT[16*36]=1600; transpose: 32*65=2080
  float* sX  = smem;
  float* sWT = smem + 1024;
  const int t  = threadIdx.x;
  const int b  = blockIdx.y;
  const int n0 = blockIdx.x * 64;
  const int cg = t >> 3;           // d 0..31
  const int np = t & 7;            // pixel octet

  float acc[8];
  #pragma unroll
  for (int j = 0; j < 8; j++) acc[j] = 0.f;

  const float* Xb = X + (size_t)b * CDIM * NPIX;

  for (int cs = 0; cs < CDIM; cs += 16) {
    __syncthreads();
    #pragma unroll
    for (int i = 0; i < 4; i++) {
      int f = i * 256 + t;
      int r = f >> 6, col = f & 63;
      sX[r * 64 + col] = Xb[(size_t)(cs + r) * NPIX + n0 + col];
    }
    #pragma unroll
    for (int i = 0; i < 2; i++) {
      int f = i * 256 + t;
      int c = f >> 4, cr = f & 15;
      sWT[cr * 36 + c] = W[c * CDIM + cs + cr];
    }
    __syncthreads();
    #pragma unroll
    for (int cp = 0; cp < 16; cp++) {
      float4 x0 = *(const float4*)&sX[cp * 64 + np * 8];
      float4 x1 = *(const float4*)&sX[cp * 64 + np * 8 + 4];
      float wv = sWT[cp * 36 + cg];
      acc[0] = fmaf(wv, x0.x, acc[0]); acc[1] = fmaf(wv, x0.y, acc[1]);
      acc[2] = fmaf(wv, x0.z, acc[2]); acc[3] = fmaf(wv, x0.w, acc[3]);
      acc[4] = fmaf(wv, x1.x, acc[4]); acc[5] = fmaf(wv, x1.y, acc[5]);
      acc[6] = fmaf(wv, x1.z, acc[6]); acc[7] = fmaf(wv, x1.w, acc[7]);
    }
  }

  // transpose epilogue: [d][n] in LDS -> coalesced [n][d] u16x8 stores
  __syncthreads();
  const float bv = bias[cg];
  #pragma unroll
  for (int j = 0; j < 8; j++) smem[cg * 65 + np * 8 + j] = acc[j] + bv;
  __syncthreads();
  const int n  = t >> 2;
  const int dq = t & 3;
  u16x8 hv, lv;
  #pragma unroll
  for (int i = 0; i < 8; i++) {
    float o = smem[(dq * 8 + i) * 65 + n];
    unsigned short h = f2bf(o);
    hv[i] = h;
    lv[i] = f2bf(o - bf2f(h));
  }
  const size_t base = ((size_t)b * NPIX + n0 + n) * DQK + dq * 8;
  *(u16x8*)&OH[base] = hv;
  *(u16x8*)&OL[base] = lv;
}

// ============================================================================
// v projection (M=256): out plane [b][c][n] bf16 (hi only — PV is 2-product).
// 32-pixel tiles -> 512 blocks -> 2 blocks/CU. Thread owns 4c x 8n.
// ============================================================================
__global__ __launch_bounds__(256, 2)
void vproj_kernel(const float* __restrict__ X, const float* __restrict__ W,
                  const float* __restrict__ bias, unsigned short* __restrict__ OH) {
  __shared__ float sX[16 * 32];
  __shared__ float sWT[16 * 260];
  const int t  = threadIdx.x;
  const int b  = blockIdx.y;
  const int n0 = blockIdx.x * 32;
  const int cg = t >> 2;           // channel quad 0..63
  const int np = t & 3;            // pixel octet

  float acc[4][8];
  #pragma unroll
  for (int a = 0; a < 4; a++)
    #pragma unroll
    for (int j = 0; j < 8; j++) acc[a][j] = 0.f;

  const float* Xb = X + (size_t)b * CDIM * NPIX;

  for (int cs = 0; cs < CDIM; cs += 16) {
    __syncthreads();
    #pragma unroll
    for (int i = 0; i < 2; i++) {
      int f = i * 256 + t;
      int r = f >> 5, col = f & 31;
      sX[r * 32 + col] = Xb[(size_t)(cs + r) * NPIX + n0 + col];
    }
    #pragma unroll
    for (int i = 0; i < 16; i++) {
      int f = i * 256 + t;
      int c = f >> 4, cr = f & 15;
      sWT[cr * 260 + c] = W[c * CDIM + cs + cr];
    }
    __syncthreads();
    #pragma unroll
    for (int cp = 0; cp < 16; cp++) {
      float4 x0 = *(const float4*)&sX[cp * 32 + np * 8];
      float4 x1 = *(const float4*)&sX[cp * 32 + np * 8 + 4];
      float4 w4 = *(const float4*)&sWT[cp * 260 + cg * 4];
      float wr[4] = {w4.x, w4.y, w4.z, w4.w};
      float xr[8] = {x0.x, x0.y, x0.z, x0.w, x1.x, x1.y, x1.z, x1.w};
      #pragma unroll
      for (int a = 0; a < 4; a++)
        #pragma unroll
        for (int j = 0; j < 8; j++)
          acc[a][j] = fmaf(wr[a], xr[j], acc[a][j]);
    }
  }

  #pragma unroll
  for (int a = 0; a < 4; a++) {
    const int c = cg * 4 + a;
    const float bv = bias[c];
    u16x8 hv;
    #pragma unroll
    for (int j = 0; j < 8; j++) hv[j] = f2bf(acc[a][j] + bv);
    *(u16x8*)&OH[((size_t)b * CDIM + c) * NPIX + n0 + np * 8] = hv;
  }
}

// ============================================================================
// MFMA flash attention. Grid 512 = 4 batches x 128 q-tiles(32). 4 waves.
// TK=128/iter, 32 iters, 2 barriers/iter. Wave w owns key strip [32w,32w+32)
// (QK^T 3-product + softmax) AND c-rows {64w+ln, 64w+32+ln} for PV.
// V frags read DIRECTLY from global [c][m] (L2-resident; no LDS staging).
// PV = (P_hi + P_lo) . V_hi (2-product). P transposed via swizzled LDS.
// K frags for tile kt+1 prefetched during PV of tile kt.
// ============================================================================
__global__ __launch_bounds__(256, 2)
void attn_kernel(const unsigned short* __restrict__ QH, const unsigned short* __restrict__ QL,
                 const unsigned short* __restrict__ KH, const unsigned short* __restrict__ KL,
                 const unsigned short* __restrict__ VH,
                 float* __restrict__ out) {
  __shared__ __attribute__((aligned(16))) unsigned short sPH[32 * 128];  // P hi [n][m]
  __shared__ __attribute__((aligned(16))) unsigned short sPL[32 * 128];  // P lo [n][m]
  __shared__ __attribute__((aligned(16))) float sPM[4][32];              // per-strip row max
  __shared__ __attribute__((aligned(16))) float sL[4][32];               // per-strip denom

  const int t  = threadIdx.x;
  const int w  = t >> 6;        // wave 0..3
  const int l  = t & 63;
  const int ln = l & 31;        // n-col (S^T) / n-row (PV A) / c-lane (PV B)
  const int g  = l >> 5;        // frag k-group / D-half

  const int bid = blockIdx.x;
  const int xcd = bid & 7;                       // round-robin dispatch -> XCD
  const int b   = xcd >> 1;                      // batch pinned to XCD pair
  const int qt  = ((bid >> 3) << 1) | (xcd & 1);
  const int n0  = qt * 32;

  // Q fragments (all waves; B operand of S^T)
  short8v qh[2], ql[2];
  {
    const size_t qb = ((size_t)b * NPIX + n0 + ln) * DQK + 8 * g;
    qh[0] = *(const short8v*)&QH[qb];  qh[1] = *(const short8v*)&QH[qb + 16];
    ql[0] = *(const short8v*)&QL[qb];  ql[1] = *(const short8v*)&QL[qb + 16];
  }

  f32x16 acc0, acc1;
  float m_acc[16], alpha[16];
  #pragma unroll
  for (int r = 0; r < 16; ++r) { acc0[r] = 0.f; acc1[r] = 0.f; m_acc[r] = -INFINITY; }
  float m_s = -INFINITY, l_part = 0.f;

  const int swz  = ln & 7;
  const int prow = ln * 128;    // halfword row offset in sPH/sPL

  // K prefetch (tile 0): strip rows 32w + ln
  short8v kh0, kh1, kl0, kl1;
  {
    const size_t kb = ((size_t)b * NPIX + 32 * w + ln) * DQK + 8 * g;
    kh0 = *(const short8v*)&KH[kb];  kh1 = *(const short8v*)&KH[kb + 16];
    kl0 = *(const short8v*)&KL[kb];  kl1 = *(const short8v*)&KL[kb + 16];
  }

  for (int kt = 0; kt < 32; ++kt) {
    const int m0 = kt * 128;

    // ---- A: S^T = K.Q^T for own 32-key strip (3-product split) ----
    f32x16 sT;
    #pragma unroll
    for (int r = 0; r < 16; ++r) sT[r] = 0.f;
    sT = MFMA32(kh0, qh[0], sT);
    sT = MFMA32(kh0, ql[0], sT);
    sT = MFMA32(kl0, qh[0], sT);
    sT = MFMA32(kh1, qh[1], sT);
    sT = MFMA32(kh1, ql[1], sT);
    sT = MFMA32(kl1, qh[1], sT);
    float pm = sT[0];
    #pragma unroll
    for (int r = 1; r < 16; ++r) pm = fmaxf(pm, sT[r]);
    pm = fmaxf(pm, __shfl_xor(pm, 32));
    if (l < 32) sPM[w][l] = pm;

    __syncthreads();  // [1] sPM ready; prev-iter P consumers done

    // ---- B: V frag loads (global, issued early), softmax, P write, rescale ----
    short8v va[8], vb[8];
    {
      const size_t v0 = ((size_t)b * CDIM + 64 * w + ln) * NPIX + m0 + 8 * g;
      const size_t v1 = v0 + (size_t)32 * NPIX;
      #pragma unroll
      for (int s = 0; s < 8; ++s) {
        va[s] = *(const short8v*)&VH[v0 + 16 * s];
        vb[s] = *(const short8v*)&VH[v1 + 16 * s];
      }
    }
    {
      const float mo = m_s;
      float mN = fmaxf(fmaxf(sPM[0][ln], sPM[1][ln]), fmaxf(sPM[2][ln], sPM[3][ln]));
      mN = fmaxf(mo, mN);
      m_s = mN;
      float ps = 0.f;
      unsigned int hw[8], lw[8];
      #pragma unroll
      for (int r = 0; r < 16; r += 2) {
        float p0 = __expf(sT[r] - mN);
        float p1 = __expf(sT[r + 1] - mN);
        ps += p0 + p1;
        unsigned short h0 = f2bf(p0), h1 = f2bf(p1);
        hw[r >> 1] = (unsigned int)h0 | ((unsigned int)h1 << 16);
        lw[r >> 1] = (unsigned int)f2bf(p0 - bf2f(h0)) |
                     ((unsigned int)f2bf(p1 - bf2f(h1)) << 16);
      }
      ps += __shfl_xor(ps, 32);
      l_part = l_part * __expf(mo - mN) + ps;
      // P stores: 4 uint2 per lane, XOR-swizzled 16B chunks
      #pragma unroll
      for (int i = 0; i < 4; ++i) {
        const int c   = (4 * w + i) ^ swz;
        const int off = prow + c * 8 + 4 * g;
        *(uint2*)&sPH[off] = make_uint2(hw[2 * i], hw[2 * i + 1]);
        *(uint2*)&sPL[off] = make_uint2(lw[2 * i], lw[2 * i + 1]);
      }
    }
    // rescale factors (acc rows n = (r&3)+8(r>>2)+4g)
    #pragma unroll
    for (int rq = 0; rq < 4; ++rq) {
      const float4 p0 = *(const float4*)&sPM[0][8 * rq + 4 * g];
      const float4 p1 = *(const float4*)&sPM[1][8 * rq + 4 * g];
      const float4 p2 = *(const float4*)&sPM[2][8 * rq + 4 * g];
      const float4 p3 = *(const float4*)&sPM[3][8 * rq + 4 * g];
      float mn;
      mn = fmaxf(m_acc[4*rq+0], fmaxf(fmaxf(p0.x, p1.x), fmaxf(p2.x, p3.x)));
      alpha[4*rq+0] = __expf(m_acc[4*rq+0] - mn); m_acc[4*rq+0] = mn;
      mn = fmaxf(m_acc[4*rq+1], fmaxf(fmaxf(p0.y, p1.y), fmaxf(p2.y, p3.y)));
      alpha[4*rq+1] = __expf(m_acc[4*rq+1] - mn); m_acc[4*rq+1] = mn;
      mn = fmaxf(m_acc[4*rq+2], fmaxf(fmaxf(p0.z, p1.z), fmaxf(p2.z, p3.z)));
      alpha[4*rq+2] = __expf(m_acc[4*rq+2] - mn); m_acc[4*rq+2] = mn;
      mn = fmaxf(m_acc[4*rq+3], fmaxf(fmaxf(p0.w, p1.w), fmaxf(p2.w, p3.w)));
      alpha[4*rq+3] = __expf(m_acc[4*rq+3] - mn); m_acc[4*rq+3] = mn;
    }
    #pragma unroll
    for (int r = 0; r < 16; ++r) { acc0[r] *= alpha[r]; acc1[r] *= alpha[r]; }

    __syncthreads();  // [2] P ready

    // ---- C: K prefetch (kt+1), P frag reads, PV MFMAs ----
    {
      const int ktn = (kt + 1) & 31;
      const size_t kb = ((size_t)b * NPIX + ktn * 128 + 32 * w + ln) * DQK + 8 * g;
      kh0 = *(const short8v*)&KH[kb];  kh1 = *(const short8v*)&KH[kb + 16];
      kl0 = *(const short8v*)&KL[kb];  kl1 = *(const short8v*)&KL[kb + 16];
    }
    #pragma unroll
    for (int s = 0; s < 8; ++s) {
      const int off = prow + (((2 * s + g) ^ swz) << 3);
      short8v pa = *(const short8v*)&sPH[off];
      short8v pl = *(const short8v*)&sPL[off];
      acc0 = MFMA32(pa, va[s], acc0);
      acc0 = MFMA32(pl, va[s], acc0);
      acc1 = MFMA32(pa, vb[s], acc1);
      acc1 = MFMA32(pl, vb[s], acc1);
    }
  }

  // ---- epilogue: merge strip denominators, divide, store ----
  if (l < 32) sL[w][l] = l_part;
  __syncthreads();

  float4 linv[4];
  #pragma unroll
  for (int rq = 0; rq < 4; ++rq) {
    const float4 a0 = *(const float4*)&sL[0][8 * rq + 4 * g];
    const float4 a1 = *(const float4*)&sL[1][8 * rq + 4 * g];
    const float4 a2 = *(const float4*)&sL[2][8 * rq + 4 * g];
    const float4 a3 = *(const float4*)&sL[3][8 * rq + 4 * g];
    linv[rq].x = 1.f / (a0.x + a1.x + a2.x + a3.x);
    linv[rq].y = 1.f / (a0.y + a1.y + a2.y + a3.y);
    linv[rq].z = 1.f / (a0.z + a1.z + a2.z + a3.z);
    linv[rq].w = 1.f / (a0.w + a1.w + a2.w + a3.w);
  }

  const int c0 = 64 * w + ln;
  float* orow0 = out + ((size_t)b * CDIM + c0) * NPIX + n0;
  float* orow1 = orow0 + (size_t)32 * NPIX;
  #pragma unroll
  for (int rq = 0; rq < 4; ++rq) {
    float4 o0, o1;
    o0.x = acc0[4*rq+0] * linv[rq].x;  o1.x = acc1[4*rq+0] * linv[rq].x;
    o0.y = acc0[4*rq+1] * linv[rq].y;  o1.y = acc1[4*rq+1] * linv[rq].y;
    o0.z = acc0[4*rq+2] * linv[rq].z;  o1.z = acc1[4*rq+2] * linv[rq].z;
    o0.w = acc0[4*rq+3] * linv[rq].w;  o1.w = acc1[4*rq+3] * linv[rq].w;
    *(float4*)&orow0[8 * rq + 4 * g] = o0;
    *(float4*)&orow1[8 * rq + 4 * g] = o1;
  }
}

// ============================================================================
extern "C" void kernel_launch(void* const* d_in, const int* in_sizes, int n_in,
                              void* d_out, int out_size, void* d_ws, size_t ws_size,
                              hipStream_t stream) {
  const float* f1 = (const float*)d_in[0];
  const float* f2 = (const float*)d_in[1];
  const float* Wq = (const float*)d_in[2];
  const float* bq = (const float*)d_in[3];
  const float* Wk = (const float*)d_in[4];
  const float* bk = (const float*)d_in[5];
  const float* Wv = (const float*)d_in[6];
  const float* bv = (const float*)d_in[7];

  unsigned short* ws = (unsigned short*)d_ws;
  unsigned short* QH = ws;                  // [4][4096][32]
  unsigned short* QL = ws + 524288;
  unsigned short* KH = ws + 1048576;
  unsigned short* KL = ws + 1572864;
  unsigned short* VH = ws + 2097152;        // [4][256][4096]  (12 MiB total)

  qkproj_kernel<<<dim3(NPIX / 64, NB), 256, 0, stream>>>(f1, Wq, bq, QH, QL);
  qkproj_kernel<<<dim3(NPIX / 64, NB), 256, 0, stream>>>(f2, Wk, bk, KH, KL);
  vproj_kernel <<<dim3(NPIX / 32, NB), 256, 0, stream>>>(f2, Wv, bv, VH);

  attn_kernel<<<dim3(512), 256, 0, stream>>>(QH, QL, KH, KL, VH, (float*)d_out);
}

// Round 7
// 265.482 us; speedup vs baseline: 3.0690x; 1.1657x over previous
//
#include <hip/hip_runtime.h>
#include <math.h>

#define NPIX 4096   // H*W
#define NB   4      // batch
#define CDIM 256
#define DQK  32

typedef short short8v __attribute__((ext_vector_type(8)));   // 8 bf16 (MFMA A/B frag)
typedef float f32x16  __attribute__((ext_vector_type(16)));  // 32x32 MFMA C/D frag
typedef unsigned short u16x8 __attribute__((ext_vector_type(8)));
typedef unsigned int   uint4v __attribute__((ext_vector_type(4)));

// RNE float -> bf16 (finite inputs only)
__device__ __forceinline__ unsigned short f2bf(float x) {
  unsigned int u = __float_as_uint(x);
  u += 0x7fffu + ((u >> 16) & 1u);
  return (unsigned short)(u >> 16);
}
__device__ __forceinline__ float bf2f(unsigned short h) {
  return __uint_as_float(((unsigned int)h) << 16);
}
__device__ __forceinline__ short8v frag_from_words(unsigned int a, unsigned int b,
                                                   unsigned int c, unsigned int d) {
  union { uint4v u; short8v s; } cv;
  cv.u[0] = a; cv.u[1] = b; cv.u[2] = c; cv.u[3] = d;
  return cv.s;
}
// 8 fp32 -> bf16 hi/lo fragments
__device__ __forceinline__ void cvt8(const float4& a, const float4& b,
                                     short8v& H, short8v& L) {
  float v[8] = {a.x, a.y, a.z, a.w, b.x, b.y, b.z, b.w};
  #pragma unroll
  for (int j = 0; j < 8; ++j) {
    unsigned short h = f2bf(v[j]);
    H[j] = (short)h;
    L[j] = (short)f2bf(v[j] - bf2f(h));
  }
}

#define MFMA32(A, B, C) __builtin_amdgcn_mfma_f32_32x32x16_bf16((A), (B), (C), 0, 0, 0)

// staged-X^T swizzled float index: row n (128B rows), k-in-chunk32 c
#define SWZF(n, c) ((n) * 32 + ((((c) >> 2) ^ ((n) & 7)) << 2) + ((c) & 3))

// ============================================================================
// Weight conversion: fp32 W -> bf16 hi/lo planes (one-time, tiny).
// ============================================================================
__global__ void wconv_kernel(const float* __restrict__ Wq, const float* __restrict__ Wk,
                             const float* __restrict__ Wv,
                             unsigned short* __restrict__ WqH, unsigned short* __restrict__ WqL,
                             unsigned short* __restrict__ WkH, unsigned short* __restrict__ WkL,
                             unsigned short* __restrict__ WvH, unsigned short* __restrict__ WvL) {
  const int i = blockIdx.x * 256 + threadIdx.x;
  if (i < DQK * CDIM) {
    float q = Wq[i]; unsigned short h = f2bf(q);
    WqH[i] = h; WqL[i] = f2bf(q - bf2f(h));
    float k = Wk[i]; h = f2bf(k);
    WkH[i] = h; WkL[i] = f2bf(k - bf2f(h));
  }
  if (i < CDIM * CDIM) {
    float v = Wv[i]; unsigned short h = f2bf(v);
    WvH[i] = h; WvL[i] = f2bf(v - bf2f(h));
  }
}

// ============================================================================
// q/k projection via MFMA (3-product bf16 split): out planes [b][n][32] hi/lo.
// D[n][d]: A = X^T slab (LDS, f32 swizzled, converted in-reg), B = W rows (bf16
// planes, global/L2). Block = 128 n x 32 d; wave w owns n-rows [32w,32w+32).
// blockIdx.z: 0 = q (f1,Wq), 1 = k (f2,Wk). Grid (32, NB, 2).
// ============================================================================
__global__ __launch_bounds__(256, 2)
void qkproj_kernel(const float* __restrict__ F1, const float* __restrict__ F2,
                   const unsigned short* __restrict__ WqH, const unsigned short* __restrict__ WqL,
                   const unsigned short* __restrict__ WkH, const unsigned short* __restrict__ WkL,
                   const float* __restrict__ bq, const float* __restrict__ bk,
                   unsigned short* __restrict__ QH, unsigned short* __restrict__ QL,
                   unsigned short* __restrict__ KH, unsigned short* __restrict__ KL) {
  __shared__ float sXT[128 * 32];   // [n][k] swizzled, 16 KB
  const int t  = threadIdx.x;
  const int w  = t >> 6;
  const int l  = t & 63;
  const int ln = l & 31;
  const int g  = l >> 5;
  const int b  = blockIdx.y;
  const int n0 = blockIdx.x * 128;
  const int z  = blockIdx.z;

  const float* X = z ? F2 : F1;
  const unsigned short* WH = z ? WkH : WqH;
  const unsigned short* WL = z ? WkL : WqL;
  const float* bias = z ? bk : bq;
  unsigned short* OH = z ? KH : QH;
  unsigned short* OL = z ? KL : QL;

  const float* Xb = X + (size_t)b * CDIM * NPIX;

  f32x16 acc;
  #pragma unroll
  for (int r = 0; r < 16; ++r) acc[r] = 0.f;

  const int sn = t & 127;        // staging n
  const int sc0 = t >> 7;        // staging c base (0/1)
  const int row = 32 * w + ln;   // this lane's A row (n within block)

  for (int kc = 0; kc < CDIM; kc += 32) {
    __syncthreads();
    #pragma unroll
    for (int i = 0; i < 16; ++i) {
      const int c = 2 * i + sc0;
      sXT[SWZF(sn, c)] = Xb[(size_t)(kc + c) * NPIX + n0 + sn];
    }
    __syncthreads();
    #pragma unroll
    for (int ks = 0; ks < 2; ++ks) {
      const int u = g + 2 * ks;
      float4 a0 = *(const float4*)&sXT[row * 32 + ((((2 * u)    ) ^ (row & 7)) << 2)];
      float4 a1 = *(const float4*)&sXT[row * 32 + ((((2 * u) + 1) ^ (row & 7)) << 2)];
      short8v Ah, Al;
      cvt8(a0, a1, Ah, Al);
      const size_t wb = (size_t)ln * CDIM + kc + 16 * ks + 8 * g;
      short8v Bh = *(const short8v*)&WH[wb];
      short8v Bl = *(const short8v*)&WL[wb];
      acc = MFMA32(Ah, Bh, acc);
      acc = MFMA32(Ah, Bl, acc);
      acc = MFMA32(Al, Bh, acc);
    }
  }

  const float bv = bias[ln];
  #pragma unroll
  for (int r = 0; r < 16; ++r) {
    const int n = n0 + 32 * w + (r & 3) + 8 * (r >> 2) + 4 * g;
    const float o = acc[r] + bv;
    const unsigned short h = f2bf(o);
    const size_t idx = ((size_t)b * NPIX + n) * DQK + ln;
    OH[idx] = h;
    OL[idx] = f2bf(o - bf2f(h));
  }
}

// ============================================================================
// v projection via MFMA: out plane [b][c][n] bf16 hi. D[c][n]: A = Wv rows
// (bf16 planes), B = X^T slab. Block = 256 c x 32 n; wave w: c-blocks {2w,2w+1}.
// Grid (128, NB).
// ============================================================================
__global__ __launch_bounds__(256, 2)
void vproj_kernel(const float* __restrict__ X,
                  const unsigned short* __restrict__ WvH, const unsigned short* __restrict__ WvL,
                  const float* __restrict__ bias, unsigned short* __restrict__ VH) {
  __shared__ float sXT[32 * 32];    // [n][k] swizzled, 4 KB
  const int t  = threadIdx.x;
  const int w  = t >> 6;
  const int l  = t & 63;
  const int ln = l & 31;
  const int g  = l >> 5;
  const int b  = blockIdx.y;
  const int n0 = blockIdx.x * 32;

  const float* Xb = X + (size_t)b * CDIM * NPIX;

  f32x16 acc0, acc1;
  #pragma unroll
  for (int r = 0; r < 16; ++r) { acc0[r] = 0.f; acc1[r] = 0.f; }

  const int sn = t & 31;
  const int sc0 = t >> 5;   // 0..7

  for (int kc = 0; kc < CDIM; kc += 32) {
    __syncthreads();
    #pragma unroll
    for (int i = 0; i < 4; ++i) {
      const int c = 8 * i + sc0;
      sXT[SWZF(sn, c)] = Xb[(size_t)(kc + c) * NPIX + n0 + sn];
    }
    __syncthreads();
    #pragma unroll
    for (int ks = 0; ks < 2; ++ks) {
      const int u = g + 2 * ks;
      float4 b0 = *(const float4*)&sXT[ln * 32 + ((((2 * u)    ) ^ (ln & 7)) << 2)];
      float4 b1 = *(const float4*)&sXT[ln * 32 + ((((2 * u) + 1) ^ (ln & 7)) << 2)];
      short8v Bh, Bl;
      cvt8(b0, b1, Bh, Bl);
      const size_t wb0 = (size_t)(32 * (2 * w)     + ln) * CDIM + kc + 16 * ks + 8 * g;
      const size_t wb1 = (size_t)(32 * (2 * w + 1) + ln) * CDIM + kc + 16 * ks + 8 * g;
      short8v Ah0 = *(const short8v*)&WvH[wb0];
      short8v Al0 = *(const short8v*)&WvL[wb0];
      short8v Ah1 = *(const short8v*)&WvH[wb1];
      short8v Al1 = *(const short8v*)&WvL[wb1];
      acc0 = MFMA32(Ah0, Bh, acc0);
      acc0 = MFMA32(Ah0, Bl, acc0);
      acc0 = MFMA32(Al0, Bh, acc0);
      acc1 = MFMA32(Ah1, Bh, acc1);
      acc1 = MFMA32(Ah1, Bl, acc1);
      acc1 = MFMA32(Al1, Bh, acc1);
    }
  }

  #pragma unroll
  for (int j = 0; j < 2; ++j) {
    const f32x16& a = j ? acc1 : acc0;
    #pragma unroll
    for (int r = 0; r < 16; ++r) {
      const int c = 32 * (2 * w + j) + (r & 3) + 8 * (r >> 2) + 4 * g;
      VH[((size_t)b * CDIM + c) * NPIX + n0 + ln] = f2bf(a[r] + bias[c]);
    }
  }
}

// ============================================================================
// MFMA flash attention, wave-independent (no main-loop barriers or LDS).
// Grid 512 = 4 batches x 128 q-tiles(32); block 256 thr = 4 waves, 2 blk/CU
// (8 waves/CU = 2/SIMD -> cross-wave MFMA/VALU overlap). Wave w owns key
// split [1024w, 1024w+1024), 32 tiles of 32 keys.
//   S^T = mfma(A=K, B=Q): lane(ln,g) holds S[k in Kg][n=ln]; m,l per-lane.
//   O^T = mfma(A=V, B=P^T): acc[c][n=ln]; rescale = scalar mult per lane.
//   P^T B-frags built in-register: pack pairs -> shfl_xor(32) -> select by g.
//   Defer-max (THR=8): rescale only when tile max exceeds running max + 8.
// Epilogue: split-K merge across the 4 waves via LDS, then coalesced stores.
// ============================================================================
__global__ __launch_bounds__(256, 2)
void attn_kernel(const unsigned short* __restrict__ QH, const unsigned short* __restrict__ QL,
                 const unsigned short* __restrict__ KH, const unsigned short* __restrict__ KL,
                 const unsigned short* __restrict__ VH,
                 float* __restrict__ out) {
  __shared__ float bufA[CDIM * 32];   // 32 KB
  __shared__ float bufB[CDIM * 32];   // 32 KB
  __shared__ float sM[4][32], sL[4][32], sLinv[32];

  const int t  = threadIdx.x;
  const int w  = t >> 6;        // wave 0..3 (key split)
  const int l  = t & 63;
  const int ln = l & 31;        // n-col of both S^T and O^T
  const int g  = l >> 5;

  const int bid = blockIdx.x;
  const int xcd = bid & 7;
  const int b   = xcd >> 1;                      // batch pinned to XCD pair
  const int qt  = ((bid >> 3) << 1) | (xcd & 1);
  const int n0  = qt * 32;

  // Q fragments (B operand of S^T), persistent
  short8v qh0, qh1, ql0, ql1;
  {
    const size_t qb = ((size_t)b * NPIX + n0 + ln) * DQK + 8 * g;
    qh0 = *(const short8v*)&QH[qb];  qh1 = *(const short8v*)&QH[qb + 16];
    ql0 = *(const short8v*)&QL[qb];  ql1 = *(const short8v*)&QL[qb + 16];
  }

  f32x16 acc[8];
  #pragma unroll
  for (int cb = 0; cb < 8; ++cb)
    #pragma unroll
    for (int r = 0; r < 16; ++r) acc[cb][r] = 0.f;

  float m_r = -INFINITY, l_r = 0.f;

  const size_t kB = (size_t)b * NPIX * DQK;
  const size_t vB = (size_t)b * CDIM * NPIX;
  const int key0 = w * 1024;

  // prologue: K frags for tile 0 (A operand of S^T, row k = m0+ln)
  short8v kh0, kh1, kl0, kl1;
  {
    const size_t ka = kB + (size_t)(key0 + ln) * DQK + 8 * g;
    kh0 = *(const short8v*)&KH[ka];  kh1 = *(const short8v*)&KH[ka + 16];
    kl0 = *(const short8v*)&KL[ka];  kl1 = *(const short8v*)&KL[ka + 16];
  }

  for (int i = 0; i < 32; ++i) {
    const int m0 = key0 + 32 * i;

    // ---- S^T = K.Q^T (3-product split) ----
    f32x16 sT;
    #pragma unroll
    for (int r = 0; r < 16; ++r) sT[r] = 0.f;
    sT = MFMA32(kh0, qh0, sT);
    sT = MFMA32(kh0, ql0, sT);
    sT = MFMA32(kl0, qh0, sT);
    sT = MFMA32(kh1, qh1, sT);
    sT = MFMA32(kh1, ql1, sT);
    sT = MFMA32(kl1, qh1, sT);

    // prefetch next tile's K
    {
      const int mN = key0 + 32 * ((i + 1) & 31);
      const size_t ka = kB + (size_t)(mN + ln) * DQK + 8 * g;
      kh0 = *(const short8v*)&KH[ka];  kh1 = *(const short8v*)&KH[ka + 16];
      kl0 = *(const short8v*)&KL[ka];  kl1 = *(const short8v*)&KL[ka + 16];
    }

    // issue V frags for ks=0 (A operand of O^T: row c = 32cb+ln)
    short8v v0[8];
    {
      const size_t va = vB + (size_t)ln * NPIX + m0 + 8 * g;
      #pragma unroll
      for (int cb = 0; cb < 8; ++cb)
        v0[cb] = *(const short8v*)&VH[va + (size_t)(32 * cb) * NPIX];
    }

    // ---- per-lane online softmax (n = ln), defer-max THR=8 ----
    float pm = sT[0];
    #pragma unroll
    for (int r = 1; r < 16; ++r) pm = fmaxf(pm, sT[r]);
    pm = fmaxf(pm, __shfl_xor(pm, 32));
    if (!__all(pm <= m_r + 8.f)) {
      const float mn = fmaxf(m_r, pm);
      const float al = __expf(m_r - mn);
      #pragma unroll
      for (int cb = 0; cb < 8; ++cb)
        #pragma unroll
        for (int r = 0; r < 16; ++r) acc[cb][r] *= al;
      l_r *= al;
      m_r = mn;
    }
    float p[16];
    float ps = 0.f;
    #pragma unroll
    for (int r = 0; r < 16; ++r) { p[r] = __expf(sT[r] - m_r); ps += p[r]; }
    ps += __shfl_xor(ps, 32);
    l_r += ps;

    // ---- pack P to bf16 hi/lo words, exchange lane halves ----
    unsigned int wh[8], wl[8], xh[8], xl[8];
    #pragma unroll
    for (int u = 0; u < 8; ++u) {
      const float p0 = p[2 * u], p1 = p[2 * u + 1];
      const unsigned short h0 = f2bf(p0), h1 = f2bf(p1);
      wh[u] = (unsigned int)h0 | ((unsigned int)h1 << 16);
      wl[u] = (unsigned int)f2bf(p0 - bf2f(h0)) |
              ((unsigned int)f2bf(p1 - bf2f(h1)) << 16);
    }
    #pragma unroll
    for (int u = 0; u < 8; ++u) {
      xh[u] = __shfl_xor(wh[u], 32);
      xl[u] = __shfl_xor(wl[u], 32);
    }

    // ---- PV ks=0: B-frag = P^T[k=8g..8g+7][n=ln] ----
    {
      short8v Bh = g ? frag_from_words(xh[2], xh[3], wh[2], wh[3])
                     : frag_from_words(wh[0], wh[1], xh[0], xh[1]);
      short8v Bl = g ? frag_from_words(xl[2], xl[3], wl[2], wl[3])
                     : frag_from_words(wl[0], wl[1], xl[0], xl[1]);
      // issue V frags for ks=1 while ks=0 MFMAs run
      short8v v1[8];
      {
        const size_t va = vB + (size_t)ln * NPIX + m0 + 16 + 8 * g;
        #pragma unroll
        for (int cb = 0; cb < 8; ++cb)
          v1[cb] = *(const short8v*)&VH[va + (size_t)(32 * cb) * NPIX];
      }
      #pragma unroll
      for (int cb = 0; cb < 8; ++cb) {
        acc[cb] = MFMA32(v0[cb], Bh, acc[cb]);
        acc[cb] = MFMA32(v0[cb], Bl, acc[cb]);
      }
      // ---- PV ks=1 ----
      short8v Ch = g ? frag_from_words(xh[6], xh[7], wh[6], wh[7])
                     : frag_from_words(wh[4], wh[5], xh[4], xh[5]);
      short8v Cl = g ? frag_from_words(xl[6], xl[7], wl[6], wl[7])
                     : frag_from_words(wl[4], wl[5], xl[4], xl[5]);
      #pragma unroll
      for (int cb = 0; cb < 8; ++cb) {
        acc[cb] = MFMA32(v1[cb], Ch, acc[cb]);
        acc[cb] = MFMA32(v1[cb], Cl, acc[cb]);
      }
    }
  }

  // ---- split-K merge across waves ----
  if (g == 0) { sM[w][ln] = m_r; sL[w][ln] = l_r; }
  __syncthreads();

  float mf = fmaxf(fmaxf(sM[0][ln], sM[1][ln]), fmaxf(sM[2][ln], sM[3][ln]));
  float lf = sL[0][ln] * __expf(sM[0][ln] - mf) + sL[1][ln] * __expf(sM[1][ln] - mf)
           + sL[2][ln] * __expf(sM[2][ln] - mf) + sL[3][ln] * __expf(sM[3][ln] - mf);
  const float sc = __expf(m_r - mf);
  if (w == 0 && g == 0) sLinv[ln] = 1.f / lf;

  #pragma unroll
  for (int cb = 0; cb < 8; ++cb)
    #pragma unroll
    for (int r = 0; r < 16; ++r) acc[cb][r] *= sc;

  float* myb = (w & 1) ? bufB : bufA;
  if (w < 2) {
    #pragma unroll
    for (int cb = 0; cb < 8; ++cb)
      #pragma unroll
      for (int r = 0; r < 16; ++r) {
        const int c = 32 * cb + (r & 3) + 8 * (r >> 2) + 4 * g;
        myb[c * 32 + ln] = acc[cb][r];
      }
  }
  __syncthreads();
  if (w >= 2) {
    #pragma unroll
    for (int cb = 0; cb < 8; ++cb)
      #pragma unroll
      for (int r = 0; r < 16; ++r) {
        const int c = 32 * cb + (r & 3) + 8 * (r >> 2) + 4 * g;
        myb[c * 32 + ln] += acc[cb][r];
      }
  }
  __syncthreads();

  // normalize + store: 8 iters, thread t -> row c = 32*it + (t>>3), nq = t&7
  {
    const int nq = t & 7;
    const float4 li = *(const float4*)&sLinv[4 * nq];
    #pragma unroll
    for (int it = 0; it < 8; ++it) {
      const int c = 32 * it + (t >> 3);
      const float4 a  = *(const float4*)&bufA[c * 32 + 4 * nq];
      const float4 bb = *(const float4*)&bufB[c * 32 + 4 * nq];
      float4 o;
      o.x = (a.x + bb.x) * li.x;
      o.y = (a.y + bb.y) * li.y;
      o.z = (a.z + bb.z) * li.z;
      o.w = (a.w + bb.w) * li.w;
      *(float4*)&out[((size_t)b * CDIM + c) * NPIX + n0 + 4 * nq] = o;
    }
  }
}

// ============================================================================
extern "C" void kernel_launch(void* const* d_in, const int* in_sizes, int n_in,
                              void* d_out, int out_size, void* d_ws, size_t ws_size,
                              hipStream_t stream) {
  const float* f1 = (const float*)d_in[0];
  const float* f2 = (const float*)d_in[1];
  const float* Wq = (const float*)d_in[2];
  const float* bq = (const float*)d_in[3];
  const float* Wk = (const float*)d_in[4];
  const float* bk = (const float*)d_in[5];
  const float* Wv = (const float*)d_in[6];
  const float* bv = (const float*)d_in[7];

  unsigned short* ws = (unsigned short*)d_ws;
  unsigned short* QH  = ws;                     // [4][4096][32] per plane
  unsigned short* QL  = ws + 524288;
  unsigned short* KH  = ws + 1048576;
  unsigned short* KL  = ws + 1572864;
  unsigned short* VH  = ws + 2097152;           // [4][256][4096]
  unsigned short* WqH = ws + 6291456;           // weight planes
  unsigned short* WqL = WqH + 8192;
  unsigned short* WkH = WqL + 8192;
  unsigned short* WkL = WkH + 8192;
  unsigned short* WvH = WkL + 8192;
  unsigned short* WvL = WvH + 65536;            // ends at 12.3 MiB

  wconv_kernel<<<dim3(256), 256, 0, stream>>>(Wq, Wk, Wv, WqH, WqL, WkH, WkL, WvH, WvL);
  qkproj_kernel<<<dim3(NPIX / 128, NB, 2), 256, 0, stream>>>(
      f1, f2, WqH, WqL, WkH, WkL, bq, bk, QH, QL, KH, KL);
  vproj_kernel<<<dim3(NPIX / 32, NB), 256, 0, stream>>>(f2, WvH, WvL, bv, VH);
  attn_kernel<<<dim3(512), 256, 0, stream>>>(QH, QL, KH, KL, VH, (float*)d_out);
}

// Round 8
// 206.036 us; speedup vs baseline: 3.9545x; 1.2885x over previous
//
#include <hip/hip_runtime.h>
#include <math.h>

#define NPIX 4096   // H*W
#define NB   4      // batch
#define CDIM 256
#define DQK  32

typedef short short8v __attribute__((ext_vector_type(8)));   // 8 bf16 (MFMA A/B frag)
typedef float f32x16  __attribute__((ext_vector_type(16)));  // 32x32 MFMA C/D frag
typedef unsigned short u16x8 __attribute__((ext_vector_type(8)));
typedef unsigned int   uint4v __attribute__((ext_vector_type(4)));

// RNE float -> bf16 (finite inputs only)
__device__ __forceinline__ unsigned short f2bf(float x) {
  unsigned int u = __float_as_uint(x);
  u += 0x7fffu + ((u >> 16) & 1u);
  return (unsigned short)(u >> 16);
}
__device__ __forceinline__ float bf2f(unsigned short h) {
  return __uint_as_float(((unsigned int)h) << 16);
}
__device__ __forceinline__ short8v frag_from_words(unsigned int a, unsigned int b,
                                                   unsigned int c, unsigned int d) {
  union { uint4v u; short8v s; } cv;
  cv.u[0] = a; cv.u[1] = b; cv.u[2] = c; cv.u[3] = d;
  return cv.s;
}
// 8 fp32 -> bf16 hi/lo fragments
__device__ __forceinline__ void cvt8(const float4& a, const float4& b,
                                     short8v& H, short8v& L) {
  float v[8] = {a.x, a.y, a.z, a.w, b.x, b.y, b.z, b.w};
  #pragma unroll
  for (int j = 0; j < 8; ++j) {
    unsigned short h = f2bf(v[j]);
    H[j] = (short)h;
    L[j] = (short)f2bf(v[j] - bf2f(h));
  }
}

#define MFMA32(A, B, C) __builtin_amdgcn_mfma_f32_32x32x16_bf16((A), (B), (C), 0, 0, 0)

// staged-X^T swizzled float index: row n (128B rows), k-in-chunk32 c
#define SWZF(n, c) ((n) * 32 + ((((c) >> 2) ^ ((n) & 7)) << 2) + ((c) & 3))

// ============================================================================
// Weight packing: fp32 W -> bf16 hi/lo planes in MFMA *fragment-lane order*.
//   Wv A-frags : [cblk 8][kci 8][ks 2][lane 64][8]   (lane: c=32cblk+(l&31),
//                k=32kci+16ks+8(l>>5)+e)
//   Wq/Wk B-frags: [kci 8][ks 2][lane 64][8]         (lane: d=l&31, same k)
// Every consumer load is then a contiguous 1KB per wave.
// ============================================================================
__global__ void wpack_kernel(const float* __restrict__ Wq, const float* __restrict__ Wk,
                             const float* __restrict__ Wv,
                             unsigned short* __restrict__ WqPH, unsigned short* __restrict__ WqPL,
                             unsigned short* __restrict__ WkPH, unsigned short* __restrict__ WkPL,
                             unsigned short* __restrict__ WvPH, unsigned short* __restrict__ WvPL) {
  const int tid = blockIdx.x * 256 + threadIdx.x;   // 0..8191
  {
    const int l = tid & 63;
    int rest = tid >> 6;
    const int ks = rest & 1;  rest >>= 1;
    const int kci = rest & 7;
    const int cblk = rest >> 3;                     // 0..7
    const int c  = 32 * cblk + (l & 31);
    const int k0 = 32 * kci + 16 * ks + 8 * (l >> 5);
    u16x8 hv, lv;
    #pragma unroll
    for (int e = 0; e < 8; ++e) {
      float v = Wv[c * CDIM + k0 + e];
      unsigned short h = f2bf(v);
      hv[e] = h;
      lv[e] = f2bf(v - bf2f(h));
    }
    *(u16x8*)&WvPH[(size_t)tid * 8] = hv;
    *(u16x8*)&WvPL[(size_t)tid * 8] = lv;
  }
  if (tid < 1024) {
    const int l = tid & 63;
    int rest = tid >> 6;
    const int ks = rest & 1;
    const int kci = rest >> 1;                      // 0..7
    const int d  = l & 31;
    const int k0 = 32 * kci + 16 * ks + 8 * (l >> 5);
    u16x8 qh, ql, kh, kl;
    #pragma unroll
    for (int e = 0; e < 8; ++e) {
      float q = Wq[d * CDIM + k0 + e];
      unsigned short h = f2bf(q);
      qh[e] = h; ql[e] = f2bf(q - bf2f(h));
      float k = Wk[d * CDIM + k0 + e];
      h = f2bf(k);
      kh[e] = h; kl[e] = f2bf(k - bf2f(h));
    }
    *(u16x8*)&WqPH[(size_t)tid * 8] = qh;
    *(u16x8*)&WqPL[(size_t)tid * 8] = ql;
    *(u16x8*)&WkPH[(size_t)tid * 8] = kh;
    *(u16x8*)&WkPL[(size_t)tid * 8] = kl;
  }
}

// ============================================================================
// q/k projection via MFMA. z=0: Q -> [b][n][32] hi/lo (consumed once/block).
// z=1: K -> fragment-packed [b][mt 128][f 2][lane 64][8] hi/lo via LDS
// transpose (stride-33 rows, conflict-free). W from packed planes (coalesced).
// Block = 128 n x 32 d; grid (32, NB, 2).
// ============================================================================
__global__ __launch_bounds__(256, 2)
void qkproj_kernel(const float* __restrict__ F1, const float* __restrict__ F2,
                   const unsigned short* __restrict__ WqPH, const unsigned short* __restrict__ WqPL,
                   const unsigned short* __restrict__ WkPH, const unsigned short* __restrict__ WkPL,
                   const float* __restrict__ bq, const float* __restrict__ bk,
                   unsigned short* __restrict__ QH, unsigned short* __restrict__ QL,
                   unsigned short* __restrict__ KPH, unsigned short* __restrict__ KPL) {
  __shared__ float sXT[128 * 33];   // staging [128][32] swizzled; epilogue [128][33]
  const int t  = threadIdx.x;
  const int w  = t >> 6;
  const int l  = t & 63;
  const int ln = l & 31;
  const int g  = l >> 5;
  const int b  = blockIdx.y;
  const int n0 = blockIdx.x * 128;
  const int z  = blockIdx.z;

  const float* X = z ? F2 : F1;
  const unsigned short* WH = z ? WkPH : WqPH;
  const unsigned short* WL = z ? WkPL : WqPL;
  const float* bias = z ? bk : bq;

  const float* Xb = X + (size_t)b * CDIM * NPIX;

  f32x16 acc;
  #pragma unroll
  for (int r = 0; r < 16; ++r) acc[r] = 0.f;

  const int sn = t & 127;        // staging n
  const int sc0 = t >> 7;        // staging c base (0/1)
  const int row = 32 * w + ln;   // this lane's A row (n within block)

  for (int kci = 0; kci < 8; ++kci) {
    const int kc = kci * 32;
    __syncthreads();
    #pragma unroll
    for (int i = 0; i < 16; ++i) {
      const int c = 2 * i + sc0;
      sXT[SWZF(sn, c)] = Xb[(size_t)(kc + c) * NPIX + n0 + sn];
    }
    __syncthreads();
    #pragma unroll
    for (int ks = 0; ks < 2; ++ks) {
      const int u = g + 2 * ks;
      float4 a0 = *(const float4*)&sXT[row * 32 + ((((2 * u)    ) ^ (row & 7)) << 2)];
      float4 a1 = *(const float4*)&sXT[row * 32 + ((((2 * u) + 1) ^ (row & 7)) << 2)];
      short8v Ah, Al;
      cvt8(a0, a1, Ah, Al);
      const size_t wb = ((size_t)((kci * 2 + ks) * 64) + l) * 8;
      short8v Bh = *(const short8v*)&WH[wb];
      short8v Bl = *(const short8v*)&WL[wb];
      acc = MFMA32(Ah, Bh, acc);
      acc = MFMA32(Ah, Bl, acc);
      acc = MFMA32(Al, Bh, acc);
    }
  }

  const float bv = bias[ln];
  if (z == 0) {
    // Q: plain [n][32] hi/lo (read once per attn block)
    #pragma unroll
    for (int r = 0; r < 16; ++r) {
      const int n = n0 + 32 * w + (r & 3) + 8 * (r >> 2) + 4 * g;
      const float o = acc[r] + bv;
      const unsigned short h = f2bf(o);
      const size_t idx = ((size_t)b * NPIX + n) * DQK + ln;
      QH[idx] = h;
      QL[idx] = f2bf(o - bf2f(h));
    }
  } else {
    // K: fragment-packed via LDS transpose
    __syncthreads();
    #pragma unroll
    for (int r = 0; r < 16; ++r) {
      const int nl = 32 * w + (r & 3) + 8 * (r >> 2) + 4 * g;
      sXT[nl * 33 + ln] = acc[r] + bv;
    }
    __syncthreads();
    #pragma unroll
    for (int i = 0; i < 2; ++i) {
      const int id = 256 * i + t;        // 0..511
      const int l2 = id & 63;
      const int f  = (id >> 6) & 1;
      const int st = id >> 7;            // 0..3
      const int nl = 32 * st + (l2 & 31);
      const int d0 = 16 * f + 8 * (l2 >> 5);
      u16x8 hv, lv;
      #pragma unroll
      for (int e = 0; e < 8; ++e) {
        float o = sXT[nl * 33 + d0 + e];
        unsigned short h = f2bf(o);
        hv[e] = h;
        lv[e] = f2bf(o - bf2f(h));
      }
      const int mt = (n0 >> 5) + st;
      const size_t off = ((size_t)((b * 128 + mt) * 2 + f)) * 512 + l2 * 8;
      *(u16x8*)&KPH[off] = hv;
      *(u16x8*)&KPL[off] = lv;
    }
  }
}

// ============================================================================
// v projection via MFMA: out = fragment-packed V hi plane
// [b][mt 128][cb 8][ks 2][lane 64][8] via LDS transpose. W from packed planes.
// Block = 256 c x 32 keys (mt = n0/32); grid (128, NB).
// ============================================================================
__global__ __launch_bounds__(256, 2)
void vproj_kernel(const float* __restrict__ X,
                  const unsigned short* __restrict__ WvPH, const unsigned short* __restrict__ WvPL,
                  const float* __restrict__ bias, unsigned short* __restrict__ VPH) {
  __shared__ float sXT[32 * 32];     // staging [32n][32k] swizzled
  __shared__ float sV[256 * 33];     // epilogue transpose [c][n], 33KB
  const int t  = threadIdx.x;
  const int w  = t >> 6;
  const int l  = t & 63;
  const int ln = l & 31;
  const int g  = l >> 5;
  const int b  = blockIdx.y;
  const int n0 = blockIdx.x * 32;

  const float* Xb = X + (size_t)b * CDIM * NPIX;

  f32x16 acc0, acc1;
  #pragma unroll
  for (int r = 0; r < 16; ++r) { acc0[r] = 0.f; acc1[r] = 0.f; }

  const int sn = t & 31;
  const int sc0 = t >> 5;   // 0..7

  for (int kci = 0; kci < 8; ++kci) {
    const int kc = kci * 32;
    __syncthreads();
    #pragma unroll
    for (int i = 0; i < 4; ++i) {
      const int c = 8 * i + sc0;
      sXT[SWZF(sn, c)] = Xb[(size_t)(kc + c) * NPIX + n0 + sn];
    }
    __syncthreads();
    #pragma unroll
    for (int ks = 0; ks < 2; ++ks) {
      const int u = g + 2 * ks;
      float4 b0 = *(const float4*)&sXT[ln * 32 + ((((2 * u)    ) ^ (ln & 7)) << 2)];
      float4 b1 = *(const float4*)&sXT[ln * 32 + ((((2 * u) + 1) ^ (ln & 7)) << 2)];
      short8v Bh, Bl;
      cvt8(b0, b1, Bh, Bl);
      const size_t wb0 = ((size_t)(((2 * w    ) * 8 + kci) * 2 + ks) * 64 + l) * 8;
      const size_t wb1 = ((size_t)(((2 * w + 1) * 8 + kci) * 2 + ks) * 64 + l) * 8;
      short8v Ah0 = *(const short8v*)&WvPH[wb0];
      short8v Al0 = *(const short8v*)&WvPL[wb0];
      short8v Ah1 = *(const short8v*)&WvPH[wb1];
      short8v Al1 = *(const short8v*)&WvPL[wb1];
      acc0 = MFMA32(Ah0, Bh, acc0);
      acc0 = MFMA32(Ah0, Bl, acc0);
      acc0 = MFMA32(Al0, Bh, acc0);
      acc1 = MFMA32(Ah1, Bh, acc1);
      acc1 = MFMA32(Ah1, Bl, acc1);
      acc1 = MFMA32(Al1, Bh, acc1);
    }
  }

  // epilogue: transpose via LDS, emit fragment-packed bf16 hi plane
  __syncthreads();
  #pragma unroll
  for (int j = 0; j < 2; ++j) {
    const f32x16& a = j ? acc1 : acc0;
    const int cblk = 2 * w + j;
    #pragma unroll
    for (int r = 0; r < 16; ++r) {
      const int c = 32 * cblk + (r & 3) + 8 * (r >> 2) + 4 * g;
      sV[c * 33 + ln] = a[r] + bias[c];
    }
  }
  __syncthreads();
  const int mt = n0 >> 5;
  #pragma unroll
  for (int i = 0; i < 4; ++i) {
    const int id = 256 * i + t;          // 0..1023
    const int l2 = id & 63;
    const int ks = (id >> 6) & 1;
    const int cb = id >> 7;              // 0..7
    const int c  = 32 * cb + (l2 & 31);
    const int nn = 16 * ks + 8 * (l2 >> 5);
    u16x8 hv;
    #pragma unroll
    for (int e = 0; e < 8; ++e) hv[e] = f2bf(sV[c * 33 + nn + e]);
    const size_t off = ((size_t)(((b * 128 + mt) * 8 + cb) * 2 + ks)) * 512 + l2 * 8;
    *(u16x8*)&VPH[off] = hv;
  }
}

// ============================================================================
// MFMA flash attention, wave-independent (no main-loop barriers or LDS).
// Identical structure to round 7; K and V now read from fragment-packed
// layouts so every fragment load is one contiguous 1KB wave transaction
// (was 32-64 scattered L2 lines per load -> latency/transaction-bound).
// ============================================================================
__global__ __launch_bounds__(256, 2)
void attn_kernel(const unsigned short* __restrict__ QH, const unsigned short* __restrict__ QL,
                 const unsigned short* __restrict__ KPH, const unsigned short* __restrict__ KPL,
                 const unsigned short* __restrict__ VPH,
                 float* __restrict__ out) {
  __shared__ float bufA[CDIM * 32];   // 32 KB
  __shared__ float bufB[CDIM * 32];   // 32 KB
  __shared__ float sM[4][32], sL[4][32], sLinv[32];

  const int t  = threadIdx.x;
  const int w  = t >> 6;        // wave 0..3 (key split)
  const int l  = t & 63;
  const int ln = l & 31;        // n-col of both S^T and O^T
  const int g  = l >> 5;

  const int bid = blockIdx.x;
  const int xcd = bid & 7;
  const int b   = xcd >> 1;                      // batch pinned to XCD pair
  const int qt  = ((bid >> 3) << 1) | (xcd & 1);
  const int n0  = qt * 32;

  // Q fragments (B operand of S^T), persistent
  short8v qh0, qh1, ql0, ql1;
  {
    const size_t qb = ((size_t)b * NPIX + n0 + ln) * DQK + 8 * g;
    qh0 = *(const short8v*)&QH[qb];  qh1 = *(const short8v*)&QH[qb + 16];
    ql0 = *(const short8v*)&QL[qb];  ql1 = *(const short8v*)&QL[qb + 16];
  }

  f32x16 acc[8];
  #pragma unroll
  for (int cb = 0; cb < 8; ++cb)
    #pragma unroll
    for (int r = 0; r < 16; ++r) acc[cb][r] = 0.f;

  float m_r = -INFINITY, l_r = 0.f;

  const int mtB = b * 128;       // batch base in packed tile index
  const int mt0 = w * 32;        // this wave's first key tile

  // prologue: K frags for tile 0 (packed: 1KB contiguous per frag)
  short8v kh0, kh1, kl0, kl1;
  {
    const size_t ka = ((size_t)((mtB + mt0) * 2)) * 512 + l * 8;
    kh0 = *(const short8v*)&KPH[ka];  kh1 = *(const short8v*)&KPH[ka + 512];
    kl0 = *(const short8v*)&KPL[ka];  kl1 = *(const short8v*)&KPL[ka + 512];
  }

  for (int i = 0; i < 32; ++i) {
    const int mt = mt0 + i;

    // ---- S^T = K.Q^T (3-product split) ----
    f32x16 sT;
    #pragma unroll
    for (int r = 0; r < 16; ++r) sT[r] = 0.f;
    sT = MFMA32(kh0, qh0, sT);
    sT = MFMA32(kh0, ql0, sT);
    sT = MFMA32(kl0, qh0, sT);
    sT = MFMA32(kh1, qh1, sT);
    sT = MFMA32(kh1, ql1, sT);
    sT = MFMA32(kl1, qh1, sT);

    // prefetch next tile's K
    {
      const int mtn = mt0 + ((i + 1) & 31);
      const size_t ka = ((size_t)((mtB + mtn) * 2)) * 512 + l * 8;
      kh0 = *(const short8v*)&KPH[ka];  kh1 = *(const short8v*)&KPH[ka + 512];
      kl0 = *(const short8v*)&KPL[ka];  kl1 = *(const short8v*)&KPL[ka + 512];
    }

    // issue V frags for ks=0 (packed A-operand rows c=32cb+(l&31))
    short8v v0[8];
    {
      const size_t va = ((size_t)((mtB + mt) * 16)) * 512 + l * 8;  // cb stride=2*512
      #pragma unroll
      for (int cb = 0; cb < 8; ++cb)
        v0[cb] = *(const short8v*)&VPH[va + (size_t)cb * 1024];
    }

    // ---- per-lane online softmax (n = ln), defer-max THR=8 ----
    float pm = sT[0];
    #pragma unroll
    for (int r = 1; r < 16; ++r) pm = fmaxf(pm, sT[r]);
    pm = fmaxf(pm, __shfl_xor(pm, 32));
    if (!__all(pm <= m_r + 8.f)) {
      const float mn = fmaxf(m_r, pm);
      const float al = __expf(m_r - mn);
      #pragma unroll
      for (int cb = 0; cb < 8; ++cb)
        #pragma unroll
        for (int r = 0; r < 16; ++r) acc[cb][r] *= al;
      l_r *= al;
      m_r = mn;
    }
    float p[16];
    float ps = 0.f;
    #pragma unroll
    for (int r = 0; r < 16; ++r) { p[r] = __expf(sT[r] - m_r); ps += p[r]; }
    ps += __shfl_xor(ps, 32);
    l_r += ps;

    // ---- pack P to bf16 hi/lo words, exchange lane halves ----
    unsigned int wh[8], wl[8], xh[8], xl[8];
    #pragma unroll
    for (int u = 0; u < 8; ++u) {
      const float p0 = p[2 * u], p1 = p[2 * u + 1];
      const unsigned short h0 = f2bf(p0), h1 = f2bf(p1);
      wh[u] = (unsigned int)h0 | ((unsigned int)h1 << 16);
      wl[u] = (unsigned int)f2bf(p0 - bf2f(h0)) |
              ((unsigned int)f2bf(p1 - bf2f(h1)) << 16);
    }
    #pragma unroll
    for (int u = 0; u < 8; ++u) {
      xh[u] = __shfl_xor(wh[u], 32);
      xl[u] = __shfl_xor(wl[u], 32);
    }

    // ---- PV ks=0: B-frag = P^T[k=8g..8g+7][n=ln] ----
    {
      short8v Bh = g ? frag_from_words(xh[2], xh[3], wh[2], wh[3])
                     : frag_from_words(wh[0], wh[1], xh[0], xh[1]);
      short8v Bl = g ? frag_from_words(xl[2], xl[3], wl[2], wl[3])
                     : frag_from_words(wl[0], wl[1], xl[0], xl[1]);
      // issue V frags for ks=1 while ks=0 MFMAs run
      short8v v1[8];
      {
        const size_t va = ((size_t)((mtB + mt) * 16 + 1)) * 512 + l * 8;
        #pragma unroll
        for (int cb = 0; cb < 8; ++cb)
          v1[cb] = *(const short8v*)&VPH[va + (size_t)cb * 1024];
      }
      #pragma unroll
      for (int cb = 0; cb < 8; ++cb) {
        acc[cb] = MFMA32(v0[cb], Bh, acc[cb]);
        acc[cb] = MFMA32(v0[cb], Bl, acc[cb]);
      }
      // ---- PV ks=1 ----
      short8v Ch = g ? frag_from_words(xh[6], xh[7], wh[6], wh[7])
                     : frag_from_words(wh[4], wh[5], xh[4], xh[5]);
      short8v Cl = g ? frag_from_words(xl[6], xl[7], wl[6], wl[7])
                     : frag_from_words(wl[4], wl[5], xl[4], xl[5]);
      #pragma unroll
      for (int cb = 0; cb < 8; ++cb) {
        acc[cb] = MFMA32(v1[cb], Ch, acc[cb]);
        acc[cb] = MFMA32(v1[cb], Cl, acc[cb]);
      }
    }
  }

  // ---- split-K merge across waves ----
  if (g == 0) { sM[w][ln] = m_r; sL[w][ln] = l_r; }
  __syncthreads();

  float mf = fmaxf(fmaxf(sM[0][ln], sM[1][ln]), fmaxf(sM[2][ln], sM[3][ln]));
  float lf = sL[0][ln] * __expf(sM[0][ln] - mf) + sL[1][ln] * __expf(sM[1][ln] - mf)
           + sL[2][ln] * __expf(sM[2][ln] - mf) + sL[3][ln] * __expf(sM[3][ln] - mf);
  const float sc = __expf(m_r - mf);
  if (w == 0 && g == 0) sLinv[ln] = 1.f / lf;

  #pragma unroll
  for (int cb = 0; cb < 8; ++cb)
    #pragma unroll
    for (int r = 0; r < 16; ++r) acc[cb][r] *= sc;

  float* myb = (w & 1) ? bufB : bufA;
  if (w < 2) {
    #pragma unroll
    for (int cb = 0; cb < 8; ++cb)
      #pragma unroll
      for (int r = 0; r < 16; ++r) {
        const int c = 32 * cb + (r & 3) + 8 * (r >> 2) + 4 * g;
        myb[c * 32 + ln] = acc[cb][r];
      }
  }
  __syncthreads();
  if (w >= 2) {
    #pragma unroll
    for (int cb = 0; cb < 8; ++cb)
      #pragma unroll
      for (int r = 0; r < 16; ++r) {
        const int c = 32 * cb + (r & 3) + 8 * (r >> 2) + 4 * g;
        myb[c * 32 + ln] += acc[cb][r];
      }
  }
  __syncthreads();

  // normalize + store: 8 iters, thread t -> row c = 32*it + (t>>3), nq = t&7
  {
    const int nq = t & 7;
    const float4 li = *(const float4*)&sLinv[4 * nq];
    #pragma unroll
    for (int it = 0; it < 8; ++it) {
      const int c = 32 * it + (t >> 3);
      const float4 a  = *(const float4*)&bufA[c * 32 + 4 * nq];
      const float4 bb = *(const float4*)&bufB[c * 32 + 4 * nq];
      float4 o;
      o.x = (a.x + bb.x) * li.x;
      o.y = (a.y + bb.y) * li.y;
      o.z = (a.z + bb.z) * li.z;
      o.w = (a.w + bb.w) * li.w;
      *(float4*)&out[((size_t)b * CDIM + c) * NPIX + n0 + 4 * nq] = o;
    }
  }
}

// ============================================================================
extern "C" void kernel_launch(void* const* d_in, const int* in_sizes, int n_in,
                              void* d_out, int out_size, void* d_ws, size_t ws_size,
                              hipStream_t stream) {
  const float* f1 = (const float*)d_in[0];
  const float* f2 = (const float*)d_in[1];
  const float* Wq = (const float*)d_in[2];
  const float* bq = (const float*)d_in[3];
  const float* Wk = (const float*)d_in[4];
  const float* bk = (const float*)d_in[5];
  const float* Wv = (const float*)d_in[6];
  const float* bv = (const float*)d_in[7];

  unsigned short* ws = (unsigned short*)d_ws;
  unsigned short* QH   = ws;                    // [4][4096][32] plain
  unsigned short* QL   = ws + 524288;
  unsigned short* KPH  = ws + 1048576;          // packed [4][128][2][64][8]
  unsigned short* KPL  = ws + 1572864;
  unsigned short* VPH  = ws + 2097152;          // packed [4][128][8][2][64][8]
  unsigned short* WqPH = ws + 6291456;          // packed weight planes
  unsigned short* WqPL = WqPH + 8192;
  unsigned short* WkPH = WqPL + 8192;
  unsigned short* WkPL = WkPH + 8192;
  unsigned short* WvPH = WkPL + 8192;
  unsigned short* WvPL = WvPH + 65536;          // ends at ~12.9 MiB

  wpack_kernel<<<dim3(32), 256, 0, stream>>>(Wq, Wk, Wv,
      WqPH, WqPL, WkPH, WkPL, WvPH, WvPL);
  qkproj_kernel<<<dim3(NPIX / 128, NB, 2), 256, 0, stream>>>(
      f1, f2, WqPH, WqPL, WkPH, WkPL, bq, bk, QH, QL, KPH, KPL);
  vproj_kernel<<<dim3(NPIX / 32, NB), 256, 0, stream>>>(f2, WvPH, WvPL, bv, VPH);
  attn_kernel<<<dim3(512), 256, 0, stream>>>(QH, QL, KPH, KPL, VPH, (float*)d_out);
}